// Round 1
// baseline (80.710 us; speedup 1.0000x reference)
//
#include <hip/hip_runtime.h>
#include <cmath>

#define NGRAPHS 1024
#define ZDIM 16
#define NB 10
#define SHD 16
#define FEAT 2560   // 16 z * 10 b * 16 sh
#define CHUNK 32

// Thread ownership: tid -> (z = tid>>4, sh = tid&15); acc[10] = b dimension in regs.
// Radial basis is 2-sparse: only b in {ib, ib+1} nonzero per node, ib node-uniform.
__global__ __launch_bounds__(256) void yfe_kernel(
    const float* __restrict__ xin,
    const float* __restrict__ pos,
    const int* __restrict__ batch,
    float* __restrict__ out,
    int n_nodes)
{
    const int g = blockIdx.x;
    const int tid = threadIdx.x;

    // segment boundaries via binary search (batch sorted ascending)
    int lo = 0, hi = n_nodes;
    while (lo < hi) { int mid = (lo + hi) >> 1; if (batch[mid] < g) lo = mid + 1; else hi = mid; }
    const int start = lo;
    hi = n_nodes;
    while (lo < hi) { int mid = (lo + hi) >> 1; if (batch[mid] < g + 1) lo = mid + 1; else hi = mid; }
    const int end = lo;
    const int cnt = end - start;

    __shared__ float  s_x[CHUNK][ZDIM];
    __shared__ float  s_sh[CHUNK][SHD];
    __shared__ float2 s_bv[CHUNK];
    __shared__ int    s_ib[CHUNK];
    __shared__ __align__(16) float s_out[FEAT];

    const int zi  = tid >> 4;
    const int shi = tid & 15;
    const int l   = (shi >= 9) ? 3 : (shi >= 4) ? 2 : (shi >= 1) ? 1 : 0;
    const int m   = shi - l * l;
    const int w   = 2 * l + 1;
    const int off = (l == 0) ? 0 : (l == 1) ? 160 : (l == 2) ? 640 : 1440;
    const int fbase = off + zi * 10 * w + m;   // out index for b=0; +b*w for others

    float acc[NB];
#pragma unroll
    for (int b = 0; b < NB; ++b) acc[b] = 0.0f;

    // c = SMOOTH_FINITE_C * e^2 * sqrt(NBASIS)
    const float CB = (float)(1.14136 * 7.389056098930650 * 3.1622776601683795);

    for (int nb0 = start; nb0 < end; nb0 += CHUNK) {
        const int nrem = min(CHUNK, end - nb0);
        __syncthreads();   // protect previous iteration's LDS reads
        // stage x rows
        for (int idx = tid; idx < nrem * ZDIM; idx += 256) {
            const int c = idx >> 4, zz = idx & 15;
            s_x[c][zz] = xin[(size_t)(nb0 + c) * ZDIM + zz];
        }
        // stage spherical harmonics + sparse radial basis, one thread per node
        if (tid < nrem) {
            const int node = nb0 + tid;
            const float px = pos[node * 3 + 0];
            const float py = pos[node * 3 + 1];
            const float pz = pos[node * 3 + 2];
            const float r2 = px * px + py * py + pz * pz;
            const float rinv = rsqrtf(r2);
            const float X = px * rinv, Y = py * rinv, Z = pz * rinv;
            const float x2 = X * X, y2 = Y * Y, z2 = Z * Z;
            const float x2z2 = x2 + z2;
            const float s3  = 1.7320508075688772f;
            const float s5  = 2.2360679774997896f;
            const float s7  = 2.6457513110645907f;
            const float s15 = 3.8729833462074170f;
            const float c42_6  = 1.0801234497346435f;   // sqrt(42)/6
            const float c168_8 = 1.6201851746019651f;   // sqrt(168)/8
            const float sh2_0 = s15 * X * Z;
            const float sh2_1 = s15 * X * Y;
            const float sh2_2 = s5 * (y2 - 0.5f * x2z2);
            const float sh2_3 = s15 * Y * Z;
            const float sh2_4 = 0.5f * s15 * (z2 - x2);
            s_sh[tid][0]  = 1.0f;
            s_sh[tid][1]  = s3 * X;
            s_sh[tid][2]  = s3 * Y;
            s_sh[tid][3]  = s3 * Z;
            s_sh[tid][4]  = sh2_0;
            s_sh[tid][5]  = sh2_1;
            s_sh[tid][6]  = sh2_2;
            s_sh[tid][7]  = sh2_3;
            s_sh[tid][8]  = sh2_4;
            s_sh[tid][9]  = c42_6 * (sh2_0 * Z + sh2_4 * X);
            s_sh[tid][10] = s7 * sh2_0 * Y;
            s_sh[tid][11] = c168_8 * (4.0f * y2 - x2z2) * X;
            s_sh[tid][12] = 0.5f * s7 * Y * (2.0f * y2 - 3.0f * x2z2);
            s_sh[tid][13] = c168_8 * Z * (4.0f * y2 - x2z2);
            s_sh[tid][14] = s7 * sh2_4 * Y;
            s_sh[tid][15] = c42_6 * (sh2_4 * Z - sh2_0 * X);
            // radial basis: t = 1.1*d; active b in (t-2, t) -> at most {ib, ib+1}
            const float d = r2 * rinv;     // sqrt(r2)
            const float t = d * 1.1f;
            int ib = (int)floorf(t) - 1;
            ib = min(max(ib, 0), 8);
            float bvA = 0.0f, bvB = 0.0f;
            {
                const float u1 = t - (float)ib, u2 = (float)(ib + 2) - t;
                if (u1 > 0.0f && u2 > 0.0f) bvA = CB * expf(-1.0f / u1) * expf(-1.0f / u2);
                const float v1 = t - (float)(ib + 1), v2 = (float)(ib + 3) - t;
                if (v1 > 0.0f && v2 > 0.0f) bvB = CB * expf(-1.0f / v1) * expf(-1.0f / v2);
            }
            s_bv[tid] = make_float2(bvA, bvB);
            s_ib[tid] = ib;
        }
        __syncthreads();
        for (int c = 0; c < nrem; ++c) {
            const float q = s_x[c][zi] * s_sh[c][shi];   // broadcast-class LDS reads
            const float2 bv = s_bv[c];
            const int ib = __builtin_amdgcn_readfirstlane(s_ib[c]);  // wave-uniform -> scalar branch
            switch (ib) {
                case 0: acc[0] += q * bv.x; acc[1] += q * bv.y; break;
                case 1: acc[1] += q * bv.x; acc[2] += q * bv.y; break;
                case 2: acc[2] += q * bv.x; acc[3] += q * bv.y; break;
                case 3: acc[3] += q * bv.x; acc[4] += q * bv.y; break;
                case 4: acc[4] += q * bv.x; acc[5] += q * bv.y; break;
                case 5: acc[5] += q * bv.x; acc[6] += q * bv.y; break;
                case 6: acc[6] += q * bv.x; acc[7] += q * bv.y; break;
                case 7: acc[7] += q * bv.x; acc[8] += q * bv.y; break;
                default: acc[8] += q * bv.x; acc[9] += q * bv.y; break;
            }
        }
    }

    // mean + stage to LDS for coalesced output
    const float scale = 1.0f / (float)max(cnt, 1);
#pragma unroll
    for (int b = 0; b < NB; ++b) s_out[fbase + b * w] = acc[b] * scale;
    __syncthreads();
    float4* og4 = (float4*)(out + (size_t)g * FEAT);
    const float4* so4 = (const float4*)s_out;
    for (int i = tid; i < FEAT / 4; i += 256) og4[i] = so4[i];
}

extern "C" void kernel_launch(void* const* d_in, const int* in_sizes, int n_in,
                              void* d_out, int out_size, void* d_ws, size_t ws_size,
                              hipStream_t stream) {
    const float* x   = (const float*)d_in[0];
    const float* pos = (const float*)d_in[1];
    const int* batch = (const int*)d_in[2];
    float* out = (float*)d_out;
    const int n_nodes = in_sizes[2];
    hipLaunchKernelGGL(yfe_kernel, dim3(NGRAPHS), dim3(256), 0, stream,
                       x, pos, batch, out, n_nodes);
}

// Round 2
// 76.303 us; speedup vs baseline: 1.0578x; 1.0578x over previous
//
#include <hip/hip_runtime.h>
#include <cmath>

#define NGRAPHS 1024
#define ZDIM 16
#define NB 10
#define SHD 16
#define FEAT 2560   // 16 z * 10 b * 16 sh
#define CHUNK 64

// ---------- Kernel 1: segment starts (batch sorted ascending) ----------
// starts[g] = first node index with batch >= g; starts[NGRAPHS] = n.
__global__ __launch_bounds__(256) void seg_starts_kernel(
    const int* __restrict__ batch, int* __restrict__ starts, int n)
{
    const int i = blockIdx.x * blockDim.x + threadIdx.x;
    if (i >= n) return;
    const int b  = batch[i];
    const int bp = (i == 0) ? -1 : batch[i - 1];
    for (int g = bp + 1; g <= b; ++g) starts[g] = i;
    if (i == n - 1) {
        for (int g = b + 1; g <= NGRAPHS; ++g) starts[g] = n;
    }
}

// ---------- Kernel 2: per-graph feature accumulation ----------
// Thread ownership: tid -> (z = tid>>4, sh = tid&15); acc[10] = b dim in regs.
// Radial basis is 2-sparse: only b in {ib, ib+1} nonzero per node, ib node-uniform.
__global__ __launch_bounds__(256) void yfe_kernel(
    const float* __restrict__ xin,
    const float* __restrict__ pos,
    const int* __restrict__ starts,
    float* __restrict__ out)
{
    const int g = blockIdx.x;
    const int tid = threadIdx.x;

    const int start = starts[g];
    const int end   = starts[g + 1];
    const int cnt   = end - start;

    __shared__ __align__(16) float  s_x[CHUNK * ZDIM];
    __shared__ float  s_sh[CHUNK][SHD];
    __shared__ __align__(16) float4 s_bvib[CHUNK];   // (bvA, bvB, as_float(ib), -)
    __shared__ __align__(16) float  s_out[FEAT];

    const int zi  = tid >> 4;
    const int shi = tid & 15;
    const int l   = (shi >= 9) ? 3 : (shi >= 4) ? 2 : (shi >= 1) ? 1 : 0;
    const int m   = shi - l * l;
    const int w   = 2 * l + 1;
    const int off = (l == 0) ? 0 : (l == 1) ? 160 : (l == 2) ? 640 : 1440;
    const int fbase = off + zi * 10 * w + m;   // out index for b=0; +b*w

    float acc[NB];
#pragma unroll
    for (int b = 0; b < NB; ++b) acc[b] = 0.0f;

    // c = SMOOTH_FINITE_C * e^2 * sqrt(NBASIS)
    const float CB = (float)(1.14136 * 7.389056098930650 * 3.1622776601683795);

    for (int nb0 = start; nb0 < end; nb0 += CHUNK) {
        const int nrem = min(CHUNK, end - nb0);
        __syncthreads();   // protect previous iteration's LDS reads
        // stage x rows: flat contiguous float4 copy (nb0*16 floats = 64B aligned)
        {
            const float4* src = (const float4*)(xin + (size_t)nb0 * ZDIM);
            float4* dst = (float4*)s_x;
            const int n4 = nrem * (ZDIM / 4);
            for (int idx = tid; idx < n4; idx += 256) dst[idx] = src[idx];
        }
        // stage spherical harmonics + sparse radial basis, one thread per node
        if (tid < nrem) {
            const int node = nb0 + tid;
            const float px = pos[node * 3 + 0];
            const float py = pos[node * 3 + 1];
            const float pz = pos[node * 3 + 2];
            const float r2 = px * px + py * py + pz * pz;
            const float rinv = rsqrtf(r2);
            const float X = px * rinv, Y = py * rinv, Z = pz * rinv;
            const float x2 = X * X, y2 = Y * Y, z2 = Z * Z;
            const float x2z2 = x2 + z2;
            const float s3  = 1.7320508075688772f;
            const float s5  = 2.2360679774997896f;
            const float s7  = 2.6457513110645907f;
            const float s15 = 3.8729833462074170f;
            const float c42_6  = 1.0801234497346435f;   // sqrt(42)/6
            const float c168_8 = 1.6201851746019651f;   // sqrt(168)/8
            const float sh2_0 = s15 * X * Z;
            const float sh2_1 = s15 * X * Y;
            const float sh2_2 = s5 * (y2 - 0.5f * x2z2);
            const float sh2_3 = s15 * Y * Z;
            const float sh2_4 = 0.5f * s15 * (z2 - x2);
            s_sh[tid][0]  = 1.0f;
            s_sh[tid][1]  = s3 * X;
            s_sh[tid][2]  = s3 * Y;
            s_sh[tid][3]  = s3 * Z;
            s_sh[tid][4]  = sh2_0;
            s_sh[tid][5]  = sh2_1;
            s_sh[tid][6]  = sh2_2;
            s_sh[tid][7]  = sh2_3;
            s_sh[tid][8]  = sh2_4;
            s_sh[tid][9]  = c42_6 * (sh2_0 * Z + sh2_4 * X);
            s_sh[tid][10] = s7 * sh2_0 * Y;
            s_sh[tid][11] = c168_8 * (4.0f * y2 - x2z2) * X;
            s_sh[tid][12] = 0.5f * s7 * Y * (2.0f * y2 - 3.0f * x2z2);
            s_sh[tid][13] = c168_8 * Z * (4.0f * y2 - x2z2);
            s_sh[tid][14] = s7 * sh2_4 * Y;
            s_sh[tid][15] = c42_6 * (sh2_4 * Z - sh2_0 * X);
            // radial basis: t = 1.1*d; active b in (t-2, t) -> at most {ib, ib+1}
            const float d = r2 * rinv;     // sqrt(r2)
            const float t = d * 1.1f;
            int ib = (int)floorf(t) - 1;
            ib = min(max(ib, 0), 8);
            float bvA = 0.0f, bvB = 0.0f;
            {
                const float u1 = t - (float)ib, u2 = (float)(ib + 2) - t;
                if (u1 > 0.0f && u2 > 0.0f) bvA = CB * __expf(-1.0f / u1 - 1.0f / u2);
                const float v1 = t - (float)(ib + 1), v2 = (float)(ib + 3) - t;
                if (v1 > 0.0f && v2 > 0.0f) bvB = CB * __expf(-1.0f / v1 - 1.0f / v2);
            }
            s_bvib[tid] = make_float4(bvA, bvB, __int_as_float(ib), 0.0f);
        }
        __syncthreads();
#pragma unroll 4
        for (int c = 0; c < nrem; ++c) {
            const float q = s_x[c * ZDIM + zi] * s_sh[c][shi];  // broadcast-class LDS reads
            const float4 bv = s_bvib[c];                        // one ds_read_b128 broadcast
            const int ib = __builtin_amdgcn_readfirstlane(__float_as_int(bv.z));
            switch (ib) {
                case 0: acc[0] += q * bv.x; acc[1] += q * bv.y; break;
                case 1: acc[1] += q * bv.x; acc[2] += q * bv.y; break;
                case 2: acc[2] += q * bv.x; acc[3] += q * bv.y; break;
                case 3: acc[3] += q * bv.x; acc[4] += q * bv.y; break;
                case 4: acc[4] += q * bv.x; acc[5] += q * bv.y; break;
                case 5: acc[5] += q * bv.x; acc[6] += q * bv.y; break;
                case 6: acc[6] += q * bv.x; acc[7] += q * bv.y; break;
                case 7: acc[7] += q * bv.x; acc[8] += q * bv.y; break;
                default: acc[8] += q * bv.x; acc[9] += q * bv.y; break;
            }
        }
    }

    // mean + stage to LDS for coalesced output
    const float scale = 1.0f / (float)max(cnt, 1);
#pragma unroll
    for (int b = 0; b < NB; ++b) s_out[fbase + b * w] = acc[b] * scale;
    __syncthreads();
    float4* og4 = (float4*)(out + (size_t)g * FEAT);
    const float4* so4 = (const float4*)s_out;
    for (int i = tid; i < FEAT / 4; i += 256) og4[i] = so4[i];
}

extern "C" void kernel_launch(void* const* d_in, const int* in_sizes, int n_in,
                              void* d_out, int out_size, void* d_ws, size_t ws_size,
                              hipStream_t stream) {
    const float* x   = (const float*)d_in[0];
    const float* pos = (const float*)d_in[1];
    const int* batch = (const int*)d_in[2];
    float* out = (float*)d_out;
    int* starts = (int*)d_ws;            // NGRAPHS+1 ints of scratch
    const int n_nodes = in_sizes[2];

    hipLaunchKernelGGL(seg_starts_kernel, dim3((n_nodes + 255) / 256), dim3(256),
                       0, stream, batch, starts, n_nodes);
    hipLaunchKernelGGL(yfe_kernel, dim3(NGRAPHS), dim3(256), 0, stream,
                       x, pos, starts, out);
}

// Round 3
// 71.218 us; speedup vs baseline: 1.1333x; 1.0714x over previous
//
#include <hip/hip_runtime.h>
#include <cmath>

#define NGRAPHS 1024
#define ZDIM 16
#define NB 10
#define SHD 16
#define FEAT 2560   // 16 z * 10 b * 16 sh
#define CHUNK 128
#define CPAD (CHUNK + 4)   // +4 floats: breaks power-of-2 bank aliasing for transposed rows

// One block per graph. Thread ownership: tid -> (z = tid>>4, sh = tid&15);
// acc[10] = radial-basis dimension in registers.
// Radial basis is 2-sparse: only b in {ib, ib+1} nonzero per node, ib node-uniform.
__global__ __launch_bounds__(256) void yfe_kernel(
    const float* __restrict__ xin,
    const float* __restrict__ pos,
    const int* __restrict__ batch,
    float* __restrict__ out,
    int n_nodes)
{
    const int g = blockIdx.x;
    const int tid = threadIdx.x;
    const int n = n_nodes;

    __shared__ int s_red[8];
    __shared__ __align__(16) float s_xT[ZDIM][CPAD];
    __shared__ __align__(16) float s_shT[SHD][CPAD];
    __shared__ __align__(16) float s_bvA[CHUNK];
    __shared__ __align__(16) float s_bvB[CHUNK];
    __shared__ __align__(16) int   s_ib[CHUNK];
    __shared__ __align__(16) float s_out[FEAT];

    // ---- fused segment-bound search (batch sorted ascending) ----
    // lb(v) = first i with batch[i] >= v. start = lb(g), end = lb(g+1).
    // Level 1: 256 strided probes (shared load serves both bounds).
    {
        const int pos1 = (int)(((long long)tid * n) >> 8);
        const int v = batch[pos1];
        const unsigned long long balA = __ballot(v < g);
        const unsigned long long balB = __ballot(v < g + 1);
        if ((tid & 63) == 0) {
            s_red[tid >> 6]     = __popcll(balA);
            s_red[4 + (tid >> 6)] = __popcll(balB);
        }
    }
    __syncthreads();
    int start, end;
    {
        const int KA = s_red[0] + s_red[1] + s_red[2] + s_red[3];
        const int KB = s_red[4] + s_red[5] + s_red[6] + s_red[7];
        const int loA = (KA == 0) ? 0 : (int)(((long long)(KA - 1) * n) >> 8) + 1;
        const int hiA = (KA == 256) ? n : (int)(((long long)KA * n) >> 8);
        const int loB = (KB == 0) ? 0 : (int)(((long long)(KB - 1) * n) >> 8) + 1;
        const int hiB = (KB == 256) ? n : (int)(((long long)KB * n) >> 8);
        __syncthreads();
        // Level 2: window width <= ceil(n/256) <= 196 < 256 threads.
        const int pA = loA + tid;
        const int pB = loB + tid;
        const int prA = (pA < hiA) ? (batch[pA] < g) : 0;
        const int prB = (pB < hiB) ? (batch[pB] < g + 1) : 0;
        const unsigned long long balA = __ballot(prA);
        const unsigned long long balB = __ballot(prB);
        if ((tid & 63) == 0) {
            s_red[tid >> 6]     = __popcll(balA);
            s_red[4 + (tid >> 6)] = __popcll(balB);
        }
        __syncthreads();
        start = loA + s_red[0] + s_red[1] + s_red[2] + s_red[3];
        end   = loB + s_red[4] + s_red[5] + s_red[6] + s_red[7];
    }
    const int cnt = end - start;

    const int zi  = tid >> 4;
    const int shi = tid & 15;
    const int l   = (shi >= 9) ? 3 : (shi >= 4) ? 2 : (shi >= 1) ? 1 : 0;
    const int m   = shi - l * l;
    const int w   = 2 * l + 1;
    const int off = (l == 0) ? 0 : (l == 1) ? 160 : (l == 2) ? 640 : 1440;
    const int fbase = off + zi * 10 * w + m;   // out index for b=0; +b*w

    float acc[NB];
#pragma unroll
    for (int b = 0; b < NB; ++b) acc[b] = 0.0f;

    // c = SMOOTH_FINITE_C * e^2 * sqrt(NBASIS)
    const float CB = (float)(1.14136 * 7.389056098930650 * 3.1622776601683795);

    for (int nb0 = start; nb0 < end; nb0 += CHUNK) {
        const int nrem  = min(CHUNK, end - nb0);
        const int nrem4 = (nrem + 3) & ~3;
        __syncthreads();   // protect previous iteration's LDS reads
        // stage x TRANSPOSED: thread handles one float4 of x (coalesced 16B/lane reads)
        for (int idx = tid; idx < nrem * 4; idx += 256) {
            const int c = idx >> 2, zq = (idx & 3) * 4;
            const float4 xv = *(const float4*)(xin + (size_t)(nb0 + c) * ZDIM + zq);
            s_xT[zq + 0][c] = xv.x;
            s_xT[zq + 1][c] = xv.y;
            s_xT[zq + 2][c] = xv.z;
            s_xT[zq + 3][c] = xv.w;
        }
        // stage spherical harmonics + sparse radial basis, one thread per node
        if (tid < nrem) {
            const int node = nb0 + tid;
            const float px = pos[node * 3 + 0];
            const float py = pos[node * 3 + 1];
            const float pz = pos[node * 3 + 2];
            const float r2 = px * px + py * py + pz * pz;
            const float rinv = rsqrtf(r2);
            const float X = px * rinv, Y = py * rinv, Z = pz * rinv;
            const float x2 = X * X, y2 = Y * Y, z2 = Z * Z;
            const float x2z2 = x2 + z2;
            const float s3  = 1.7320508075688772f;
            const float s5  = 2.2360679774997896f;
            const float s7  = 2.6457513110645907f;
            const float s15 = 3.8729833462074170f;
            const float c42_6  = 1.0801234497346435f;   // sqrt(42)/6
            const float c168_8 = 1.6201851746019651f;   // sqrt(168)/8
            const float sh2_0 = s15 * X * Z;
            const float sh2_1 = s15 * X * Y;
            const float sh2_2 = s5 * (y2 - 0.5f * x2z2);
            const float sh2_3 = s15 * Y * Z;
            const float sh2_4 = 0.5f * s15 * (z2 - x2);
            s_shT[0][tid]  = 1.0f;
            s_shT[1][tid]  = s3 * X;
            s_shT[2][tid]  = s3 * Y;
            s_shT[3][tid]  = s3 * Z;
            s_shT[4][tid]  = sh2_0;
            s_shT[5][tid]  = sh2_1;
            s_shT[6][tid]  = sh2_2;
            s_shT[7][tid]  = sh2_3;
            s_shT[8][tid]  = sh2_4;
            s_shT[9][tid]  = c42_6 * (sh2_0 * Z + sh2_4 * X);
            s_shT[10][tid] = s7 * sh2_0 * Y;
            s_shT[11][tid] = c168_8 * (4.0f * y2 - x2z2) * X;
            s_shT[12][tid] = 0.5f * s7 * Y * (2.0f * y2 - 3.0f * x2z2);
            s_shT[13][tid] = c168_8 * Z * (4.0f * y2 - x2z2);
            s_shT[14][tid] = s7 * sh2_4 * Y;
            s_shT[15][tid] = c42_6 * (sh2_4 * Z - sh2_0 * X);
            // radial basis: t = 1.1*d; active b in (t-2, t) -> at most {ib, ib+1}
            const float d = r2 * rinv;     // sqrt(r2)
            const float t = d * 1.1f;
            int ib = (int)floorf(t) - 1;
            ib = min(max(ib, 0), 8);
            float bvA = 0.0f, bvB = 0.0f;
            {
                const float u1 = t - (float)ib, u2 = (float)(ib + 2) - t;
                if (u1 > 0.0f && u2 > 0.0f) bvA = CB * __expf(-1.0f / u1 - 1.0f / u2);
                const float v1 = t - (float)(ib + 1), v2 = (float)(ib + 3) - t;
                if (v1 > 0.0f && v2 > 0.0f) bvB = CB * __expf(-1.0f / v1 - 1.0f / v2);
            }
            s_bvA[tid] = bvA;
            s_bvB[tid] = bvB;
            s_ib[tid]  = ib;
        } else if (tid < nrem4) {
            // zero-fill pad columns so the 4-wide inner loop reads finite zeros
#pragma unroll
            for (int k = 0; k < ZDIM; ++k) { s_xT[k][tid] = 0.0f; s_shT[k][tid] = 0.0f; }
            s_bvA[tid] = 0.0f;
            s_bvB[tid] = 0.0f;
            s_ib[tid]  = 0;
        }
        __syncthreads();

#define ACC1(Q, BA, BB, IBV)                                                     \
        {                                                                        \
            const int ib_ = __builtin_amdgcn_readfirstlane(IBV);                 \
            const float q_ = (Q);                                                \
            switch (ib_) {                                                       \
                case 0: acc[0] += q_ * (BA); acc[1] += q_ * (BB); break;         \
                case 1: acc[1] += q_ * (BA); acc[2] += q_ * (BB); break;         \
                case 2: acc[2] += q_ * (BA); acc[3] += q_ * (BB); break;         \
                case 3: acc[3] += q_ * (BA); acc[4] += q_ * (BB); break;         \
                case 4: acc[4] += q_ * (BA); acc[5] += q_ * (BB); break;         \
                case 5: acc[5] += q_ * (BA); acc[6] += q_ * (BB); break;         \
                case 6: acc[6] += q_ * (BA); acc[7] += q_ * (BB); break;         \
                case 7: acc[7] += q_ * (BA); acc[8] += q_ * (BB); break;         \
                default: acc[8] += q_ * (BA); acc[9] += q_ * (BB); break;        \
            }                                                                    \
        }

#pragma unroll 2
        for (int c = 0; c < nrem4; c += 4) {
            const float4 xv  = *(const float4*)&s_xT[zi][c];
            const float4 sv  = *(const float4*)&s_shT[shi][c];
            const float4 bA  = *(const float4*)&s_bvA[c];
            const float4 bB  = *(const float4*)&s_bvB[c];
            const int4   ibv = *(const int4*)&s_ib[c];
            ACC1(xv.x * sv.x, bA.x, bB.x, ibv.x);
            ACC1(xv.y * sv.y, bA.y, bB.y, ibv.y);
            ACC1(xv.z * sv.z, bA.z, bB.z, ibv.z);
            ACC1(xv.w * sv.w, bA.w, bB.w, ibv.w);
        }
#undef ACC1
    }

    // mean + stage to LDS for coalesced output
    const float scale = 1.0f / (float)max(cnt, 1);
#pragma unroll
    for (int b = 0; b < NB; ++b) s_out[fbase + b * w] = acc[b] * scale;
    __syncthreads();
    float4* og4 = (float4*)(out + (size_t)g * FEAT);
    const float4* so4 = (const float4*)s_out;
    for (int i = tid; i < FEAT / 4; i += 256) og4[i] = so4[i];
}

extern "C" void kernel_launch(void* const* d_in, const int* in_sizes, int n_in,
                              void* d_out, int out_size, void* d_ws, size_t ws_size,
                              hipStream_t stream) {
    const float* x   = (const float*)d_in[0];
    const float* pos = (const float*)d_in[1];
    const int* batch = (const int*)d_in[2];
    float* out = (float*)d_out;
    const int n_nodes = in_sizes[2];

    hipLaunchKernelGGL(yfe_kernel, dim3(NGRAPHS), dim3(256), 0, stream,
                       x, pos, batch, out, n_nodes);
}

// Round 4
// 71.089 us; speedup vs baseline: 1.1353x; 1.0018x over previous
//
#include <hip/hip_runtime.h>
#include <cmath>

#define NGRAPHS 1024
#define ZDIM 16
#define NB 10
#define SHD 16
#define FEAT 2560   // 16 z * 10 b * 16 sh
#define CHUNK 128
#define CPAD (CHUNK + 4)   // +4 floats: breaks power-of-2 bank aliasing for transposed rows

// One block per graph. Thread ownership: tid -> (z = tid>>4, sh = tid&15);
// acc[10] = radial-basis dimension in registers.
// Radial basis is 2-sparse: only b in {ib, ib+1} nonzero per node, ib node-uniform.
// bvA/bvB are pre-multiplied into the staged sh rows, so the inner loop is
// 2 FMAs per node with 3xds_read_b128 + 1xds_read_b32 per 4 nodes.
__global__ __launch_bounds__(256) void yfe_kernel(
    const float* __restrict__ xin,
    const float* __restrict__ pos,
    const int* __restrict__ batch,
    float* __restrict__ out,
    int n_nodes)
{
    const int g = blockIdx.x;
    const int tid = threadIdx.x;
    const int n = n_nodes;

    __shared__ int s_red[8];
    __shared__ __align__(16) float s_xT[ZDIM][CPAD];
    __shared__ __align__(16) float s_shA[SHD][CPAD];   // sh[m] * bvA
    __shared__ __align__(16) float s_shB[SHD][CPAD];   // sh[m] * bvB
    __shared__ __align__(16) unsigned int s_ib4[CHUNK / 4];  // 4 ib bytes per word
    __shared__ __align__(16) float s_out[FEAT];

    // ---- fused segment-bound search (batch sorted ascending) ----
    // lb(v) = first i with batch[i] >= v. start = lb(g), end = lb(g+1).
    // Level 1: 256 strided probes (shared load serves both bounds).
    {
        const int pos1 = (int)(((long long)tid * n) >> 8);
        const int v = batch[pos1];
        const unsigned long long balA = __ballot(v < g);
        const unsigned long long balB = __ballot(v < g + 1);
        if ((tid & 63) == 0) {
            s_red[tid >> 6]       = __popcll(balA);
            s_red[4 + (tid >> 6)] = __popcll(balB);
        }
    }
    __syncthreads();
    int start, end;
    {
        const int KA = s_red[0] + s_red[1] + s_red[2] + s_red[3];
        const int KB = s_red[4] + s_red[5] + s_red[6] + s_red[7];
        const int loA = (KA == 0) ? 0 : (int)(((long long)(KA - 1) * n) >> 8) + 1;
        const int hiA = (KA == 256) ? n : (int)(((long long)KA * n) >> 8);
        const int loB = (KB == 0) ? 0 : (int)(((long long)(KB - 1) * n) >> 8) + 1;
        const int hiB = (KB == 256) ? n : (int)(((long long)KB * n) >> 8);
        __syncthreads();
        // Level 2: window width <= ceil(n/256) <= 196 < 256 threads.
        const int pA = loA + tid;
        const int pB = loB + tid;
        const int prA = (pA < hiA) ? (batch[pA] < g) : 0;
        const int prB = (pB < hiB) ? (batch[pB] < g + 1) : 0;
        const unsigned long long balA = __ballot(prA);
        const unsigned long long balB = __ballot(prB);
        if ((tid & 63) == 0) {
            s_red[tid >> 6]       = __popcll(balA);
            s_red[4 + (tid >> 6)] = __popcll(balB);
        }
        __syncthreads();
        start = loA + s_red[0] + s_red[1] + s_red[2] + s_red[3];
        end   = loB + s_red[4] + s_red[5] + s_red[6] + s_red[7];
    }
    const int cnt = end - start;

    const int zi  = tid >> 4;
    const int shi = tid & 15;
    const int l   = (shi >= 9) ? 3 : (shi >= 4) ? 2 : (shi >= 1) ? 1 : 0;
    const int m   = shi - l * l;
    const int w   = 2 * l + 1;
    const int off = (l == 0) ? 0 : (l == 1) ? 160 : (l == 2) ? 640 : 1440;
    const int fbase = off + zi * 10 * w + m;   // out index for b=0; +b*w

    float acc[NB];
#pragma unroll
    for (int b = 0; b < NB; ++b) acc[b] = 0.0f;

    // c = SMOOTH_FINITE_C * e^2 * sqrt(NBASIS)
    const float CB = (float)(1.14136 * 7.389056098930650 * 3.1622776601683795);

    for (int nb0 = start; nb0 < end; nb0 += CHUNK) {
        const int nrem  = min(CHUNK, end - nb0);
        const int nrem4 = (nrem + 3) & ~3;
        __syncthreads();   // protect previous iteration's LDS reads
        // stage x TRANSPOSED: thread handles one float4 of x (coalesced 16B/lane reads)
        for (int idx = tid; idx < nrem * 4; idx += 256) {
            const int c = idx >> 2, zq = (idx & 3) * 4;
            const float4 xv = *(const float4*)(xin + (size_t)(nb0 + c) * ZDIM + zq);
            s_xT[zq + 0][c] = xv.x;
            s_xT[zq + 1][c] = xv.y;
            s_xT[zq + 2][c] = xv.z;
            s_xT[zq + 3][c] = xv.w;
        }
        // stage sh * bv (pre-multiplied) + packed ib byte, one thread per node
        if (tid < nrem) {
            const int node = nb0 + tid;
            const float px = pos[node * 3 + 0];
            const float py = pos[node * 3 + 1];
            const float pz = pos[node * 3 + 2];
            const float r2 = px * px + py * py + pz * pz;
            const float rinv = rsqrtf(r2);
            const float X = px * rinv, Y = py * rinv, Z = pz * rinv;
            const float x2 = X * X, y2 = Y * Y, z2 = Z * Z;
            const float x2z2 = x2 + z2;
            const float s3  = 1.7320508075688772f;
            const float s5  = 2.2360679774997896f;
            const float s7  = 2.6457513110645907f;
            const float s15 = 3.8729833462074170f;
            const float c42_6  = 1.0801234497346435f;   // sqrt(42)/6
            const float c168_8 = 1.6201851746019651f;   // sqrt(168)/8
            const float sh2_0 = s15 * X * Z;
            const float sh2_1 = s15 * X * Y;
            const float sh2_2 = s5 * (y2 - 0.5f * x2z2);
            const float sh2_3 = s15 * Y * Z;
            const float sh2_4 = 0.5f * s15 * (z2 - x2);
            float sh[SHD];
            sh[0]  = 1.0f;
            sh[1]  = s3 * X;
            sh[2]  = s3 * Y;
            sh[3]  = s3 * Z;
            sh[4]  = sh2_0;
            sh[5]  = sh2_1;
            sh[6]  = sh2_2;
            sh[7]  = sh2_3;
            sh[8]  = sh2_4;
            sh[9]  = c42_6 * (sh2_0 * Z + sh2_4 * X);
            sh[10] = s7 * sh2_0 * Y;
            sh[11] = c168_8 * (4.0f * y2 - x2z2) * X;
            sh[12] = 0.5f * s7 * Y * (2.0f * y2 - 3.0f * x2z2);
            sh[13] = c168_8 * Z * (4.0f * y2 - x2z2);
            sh[14] = s7 * sh2_4 * Y;
            sh[15] = c42_6 * (sh2_4 * Z - sh2_0 * X);
            // radial basis: t = 1.1*d; active b in (t-2, t) -> at most {ib, ib+1}
            const float d = r2 * rinv;     // sqrt(r2)
            const float t = d * 1.1f;
            int ib = (int)floorf(t) - 1;
            ib = min(max(ib, 0), 8);
            float bvA = 0.0f, bvB = 0.0f;
            {
                const float u1 = t - (float)ib, u2 = (float)(ib + 2) - t;
                if (u1 > 0.0f && u2 > 0.0f) bvA = CB * __expf(-1.0f / u1 - 1.0f / u2);
                const float v1 = t - (float)(ib + 1), v2 = (float)(ib + 3) - t;
                if (v1 > 0.0f && v2 > 0.0f) bvB = CB * __expf(-1.0f / v1 - 1.0f / v2);
            }
#pragma unroll
            for (int k = 0; k < SHD; ++k) {
                s_shA[k][tid] = sh[k] * bvA;
                s_shB[k][tid] = sh[k] * bvB;
            }
            ((unsigned char*)s_ib4)[tid] = (unsigned char)ib;
        } else if (tid < nrem4) {
            // zero-fill pad columns so the 4-wide inner loop reads finite zeros
            // (stale LDS could hold NaN bit patterns; 0*NaN = NaN)
#pragma unroll
            for (int k = 0; k < SHD; ++k) {
                s_xT[k][tid] = 0.0f; s_shA[k][tid] = 0.0f; s_shB[k][tid] = 0.0f;
            }
            ((unsigned char*)s_ib4)[tid] = 0;
        }
        __syncthreads();

#define ACC1(XQ, SA, SB, IB_)                                                    \
        {                                                                        \
            const float xq_ = (XQ);                                              \
            switch (IB_) {                                                       \
                case 0: acc[0] += xq_ * (SA); acc[1] += xq_ * (SB); break;       \
                case 1: acc[1] += xq_ * (SA); acc[2] += xq_ * (SB); break;       \
                case 2: acc[2] += xq_ * (SA); acc[3] += xq_ * (SB); break;       \
                case 3: acc[3] += xq_ * (SA); acc[4] += xq_ * (SB); break;       \
                case 4: acc[4] += xq_ * (SA); acc[5] += xq_ * (SB); break;       \
                case 5: acc[5] += xq_ * (SA); acc[6] += xq_ * (SB); break;       \
                case 6: acc[6] += xq_ * (SA); acc[7] += xq_ * (SB); break;       \
                case 7: acc[7] += xq_ * (SA); acc[8] += xq_ * (SB); break;       \
                default: acc[8] += xq_ * (SA); acc[9] += xq_ * (SB); break;      \
            }                                                                    \
        }

#pragma unroll 2
        for (int c = 0; c < nrem4; c += 4) {
            const float4 xv = *(const float4*)&s_xT[zi][c];
            const float4 sA = *(const float4*)&s_shA[shi][c];
            const float4 sB = *(const float4*)&s_shB[shi][c];
            const unsigned int ibw =
                (unsigned int)__builtin_amdgcn_readfirstlane((int)s_ib4[c >> 2]);
            ACC1(xv.x, sA.x, sB.x, (int)(ibw & 255u));
            ACC1(xv.y, sA.y, sB.y, (int)((ibw >> 8) & 255u));
            ACC1(xv.z, sA.z, sB.z, (int)((ibw >> 16) & 255u));
            ACC1(xv.w, sA.w, sB.w, (int)(ibw >> 24));
        }
#undef ACC1
    }

    // mean + stage to LDS for coalesced output
    const float scale = 1.0f / (float)max(cnt, 1);
#pragma unroll
    for (int b = 0; b < NB; ++b) s_out[fbase + b * w] = acc[b] * scale;
    __syncthreads();
    float4* og4 = (float4*)(out + (size_t)g * FEAT);
    const float4* so4 = (const float4*)s_out;
    for (int i = tid; i < FEAT / 4; i += 256) og4[i] = so4[i];
}

extern "C" void kernel_launch(void* const* d_in, const int* in_sizes, int n_in,
                              void* d_out, int out_size, void* d_ws, size_t ws_size,
                              hipStream_t stream) {
    const float* x   = (const float*)d_in[0];
    const float* pos = (const float*)d_in[1];
    const int* batch = (const int*)d_in[2];
    float* out = (float*)d_out;
    const int n_nodes = in_sizes[2];

    hipLaunchKernelGGL(yfe_kernel, dim3(NGRAPHS), dim3(256), 0, stream,
                       x, pos, batch, out, n_nodes);
}